// Round 3
// baseline (390.774 us; speedup 1.0000x reference)
//
#include <hip/hip_runtime.h>
#include <hip/hip_bf16.h>
#include <stdint.h>

#define TT   65536
#define NCH  16
#define CNOM 16
#define NBLK 256

typedef __bf16 bf16x8 __attribute__((ext_vector_type(8)));
typedef float  f32x4  __attribute__((ext_vector_type(4)));
typedef int    i32x4  __attribute__((ext_vector_type(4)));

__device__ __bf16 g_wih[768 * 256];
__device__ __bf16 g_whh[768 * 256];
__device__ __bf16 g_xbf[TT * 256];
// packed igates: [t][1024] bf16; unit group (wu*16+lu) has 8 slots, slot = c*2+p
__device__ __bf16 g_ig[(size_t)TT * 1024];

__device__ __forceinline__ void gl_lds16(const void* g, void* l) {
  __builtin_amdgcn_global_load_lds(
      (const __attribute__((address_space(1))) void*)(unsigned long long)(uintptr_t)g,
      (__attribute__((address_space(3))) void*)(unsigned int)(uintptr_t)l,
      16, 0, 0);
}

__device__ __forceinline__ bf16x8 as_bf16x8(i32x4 v) {
  bf16x8 r; __builtin_memcpy(&r, &v, 16); return r;
}

__global__ void prep_w(const float* __restrict__ wih, const float* __restrict__ whh) {
  const int n = 768 * 256;
  for (int i = blockIdx.x * blockDim.x + threadIdx.x; i < n; i += gridDim.x * blockDim.x) {
    g_wih[i] = (__bf16)wih[i];
    g_whh[i] = (__bf16)whh[i];
  }
}

__global__ void prep_x(const float* __restrict__ x) {
  int i = (blockIdx.x * 256 + threadIdx.x) * 8;
  float4 a0 = *(const float4*)(x + i);
  float4 a1 = *(const float4*)(x + i + 4);
  bf16x8 v;
  v[0] = (__bf16)a0.x; v[1] = (__bf16)a0.y; v[2] = (__bf16)a0.z; v[3] = (__bf16)a0.w;
  v[4] = (__bf16)a1.x; v[5] = (__bf16)a1.y; v[6] = (__bf16)a1.z; v[7] = (__bf16)a1.w;
  *(bf16x8*)(g_xbf + i) = v;
}

// phase 1: igates = x @ W_ih^T + bias, written in scan-packed layout
__global__ __launch_bounds__(256) void gemm_ig(const float* __restrict__ bias) {
  __shared__ __align__(16) __bf16 a_s[128 * 64];
  __shared__ __align__(16) __bf16 b_s[128 * 64];
  const int tid = threadIdx.x;
  const int w = tid >> 6, lane = tid & 63, l15 = lane & 15, q = lane >> 4;
  const int mt = blockIdx.x / 6, nt = blockIdx.x - mt * 6;
  const int m0 = mt * 128, n0 = nt * 128;
  const int wm = w >> 1, wn = w & 1;

  f32x4 acc[4][4];
#pragma unroll
  for (int a = 0; a < 4; ++a)
#pragma unroll
    for (int b = 0; b < 4; ++b) acc[a][b] = (f32x4){0.f, 0.f, 0.f, 0.f};

  for (int kc = 0; kc < 4; ++kc) {
#pragma unroll
    for (int i = 0; i < 4; ++i) {
      int pslot = i * 256 + tid;
      int row = pslot >> 3, cb = (pslot & 7) ^ (row & 7);
      gl_lds16((const char*)g_xbf + ((size_t)(m0 + row) * 256 + kc * 64) * 2 + cb * 16,
               (char*)a_s + (i * 256 + (tid & ~63)) * 16);
      gl_lds16((const char*)g_wih + ((size_t)(n0 + row) * 256 + kc * 64) * 2 + cb * 16,
               (char*)b_s + (i * 256 + (tid & ~63)) * 16);
    }
    __syncthreads();
#pragma unroll
    for (int ks = 0; ks < 2; ++ks) {
      bf16x8 af[4], bfr[4];
#pragma unroll
      for (int tm = 0; tm < 4; ++tm) {
        int row = wm * 64 + tm * 16 + l15;
        int cb = (ks * 4 + q) ^ (row & 7);
        af[tm] = *(const bf16x8*)((const char*)a_s + row * 128 + cb * 16);
      }
#pragma unroll
      for (int tn = 0; tn < 4; ++tn) {
        int row = wn * 64 + tn * 16 + l15;
        int cb = (ks * 4 + q) ^ (row & 7);
        bfr[tn] = *(const bf16x8*)((const char*)b_s + row * 128 + cb * 16);
      }
#pragma unroll
      for (int tm = 0; tm < 4; ++tm)
#pragma unroll
        for (int tn = 0; tn < 4; ++tn)
          acc[tm][tn] = __builtin_amdgcn_mfma_f32_16x16x32_bf16(af[tm], bfr[tn], acc[tm][tn], 0, 0, 0);
    }
    __syncthreads();
  }
  float bv[4];
#pragma unroll
  for (int tn = 0; tn < 4; ++tn) bv[tn] = bias[n0 + wn * 64 + tn * 16 + l15];
#pragma unroll
  for (int tm = 0; tm < 4; ++tm) {
#pragma unroll
    for (int tn = 0; tn < 4; ++tn) {
      int col = n0 + wn * 64 + tn * 16 + l15;
      int c = col >> 8, u = col & 255;
      int idx = ((u >> 5) * 16 + (u & 15)) * 8 + c * 2 + ((u >> 4) & 1);
#pragma unroll
      for (int r = 0; r < 4; ++r) {
        int t = m0 + wm * 64 + tm * 16 + q * 4 + r;
        g_ig[(size_t)t * 1024 + idx] = (__bf16)(acc[tm][tn][r] + bv[tn]);
      }
    }
  }
}

// phase 2: scan. W_hh pinned in VGPRs; packed igates async-staged.
__global__ __launch_bounds__(512, 2) void gru_scan(
    const float* __restrict__ state, const int* __restrict__ start,
    const float* __restrict__ bias_n, float* __restrict__ out) {
  __shared__ __align__(16) __bf16 h_s[16][264];
  __shared__ __align__(16) __bf16 ig_s[2][16 * 1024];
  __shared__ int s_arr[17];

  const int tid = threadIdx.x;
  const int w = tid >> 6, lane = tid & 63, l15 = lane & 15, q = lane >> 4;
  const int jrow0 = w * 32 + l15;

  if (tid < 17) {
    int t = (blockIdx.x * NCH + tid) * CNOM;
    if (t > 0) { while (t < TT && start[t] == 0) t++; }
    s_arr[tid] = t;
  }
  for (int i = tid; i < 16 * 264; i += 512) (&h_s[0][0])[i] = (__bf16)0.f;
  __syncthreads();

  int sa[4], len[4];
#pragma unroll
  for (int r = 0; r < 4; ++r) {
    sa[r] = s_arr[q * 4 + r];
    len[r] = s_arr[q * 4 + r + 1] - sa[r];
  }
  int ML = 0;
  for (int m = 0; m < 16; ++m) { int L = s_arr[m + 1] - s_arr[m]; ML = L > ML ? L : ML; }
  // staging geometry: chunk c = it*512+tid covers 16B at ig_s + c*16
  int sam[4];
#pragma unroll
  for (int it = 0; it < 4; ++it) sam[it] = s_arr[it * 4 + (tid >> 7)];
  const int igoff = (tid & 127) * 16;

  const int start0 = start[0];
  if (blockIdx.x == 0 && tid < 256) h_s[0][tid] = start0 ? (__bf16)0.f : (__bf16)state[tid];

  // stage igates for k=0 into buf 0
#pragma unroll
  for (int it = 0; it < 4; ++it) {
    int t = sam[it]; t = t > TT - 1 ? TT - 1 : t;
    gl_lds16((const char*)g_ig + (size_t)t * 2048 + igoff,
             (char*)&ig_s[0][0] + (it * 512 + (tid & ~63)) * 16);
  }

  // W_hh fragments, pinned so the compiler cannot re-load them per step
  i32x4 whh_i[2][3][8];
#pragma unroll
  for (int p = 0; p < 2; ++p)
#pragma unroll
    for (int c = 0; c < 3; ++c) {
      const __bf16* rp = &g_whh[(c * 256 + w * 32 + p * 16 + l15) * 256 + q * 8];
#pragma unroll
      for (int ks = 0; ks < 8; ++ks) whh_i[p][c][ks] = *(const i32x4*)(rp + ks * 32);
    }
#pragma unroll
  for (int p = 0; p < 2; ++p)
#pragma unroll
    for (int c = 0; c < 3; ++c)
#pragma unroll
      for (int ks = 0; ks < 8; ++ks) asm volatile("" : "+v"(whh_i[p][c][ks]));

  const float bn2[2] = { bias_n[jrow0], bias_n[jrow0 + 16] };

  float hreg[2][4];
#pragma unroll
  for (int p = 0; p < 2; ++p)
#pragma unroll
    for (int r = 0; r < 4; ++r) hreg[p][r] = 0.f;
  if (blockIdx.x == 0 && q == 0 && !start0) {
    hreg[0][0] = state[jrow0];
    hreg[1][0] = state[jrow0 + 16];
  }
  __syncthreads();

  for (int k = 0; k < ML; ++k) {
    const int bc = k & 1;
    // async prefetch igates(k+1) into the other buffer
#pragma unroll
    for (int it = 0; it < 4; ++it) {
      int t = sam[it] + k + 1; t = t > TT - 1 ? TT - 1 : t;
      gl_lds16((const char*)g_ig + (size_t)t * 2048 + igoff,
               (char*)&ig_s[bc ^ 1][0] + (it * 512 + (tid & ~63)) * 16);
    }
    int fnext[4];
#pragma unroll
    for (int r = 0; r < 4; ++r) {
      int t = sa[r] + k + 1; t = t > TT - 1 ? TT - 1 : t;
      fnext[r] = start[t];
    }

    f32x4 acc[2][3];
#pragma unroll
    for (int p = 0; p < 2; ++p)
#pragma unroll
      for (int c = 0; c < 3; ++c) acc[p][c] = (f32x4){0.f, 0.f, 0.f, 0.f};
#pragma unroll
    for (int ks = 0; ks < 8; ++ks) {
      bf16x8 hf = *(const bf16x8*)&h_s[l15][ks * 32 + q * 8];
#pragma unroll
      for (int p = 0; p < 2; ++p)
#pragma unroll
        for (int c = 0; c < 3; ++c)
          acc[p][c] = __builtin_amdgcn_mfma_f32_16x16x32_bf16(
              hf, as_bf16x8(whh_i[p][c][ks]), acc[p][c], 0, 0, 0);
    }

#pragma unroll
    for (int r = 0; r < 4; ++r) {
      int m = q * 4 + r;
      bf16x8 igv = *(const bf16x8*)&ig_s[bc][m * 1024 + (w * 16 + l15) * 8];
#pragma unroll
      for (int p = 0; p < 2; ++p) {
        float rp = acc[p][0][r] + (float)igv[p];
        float zp = acc[p][1][r] + (float)igv[2 + p];
        float hv = acc[p][2][r] + bn2[p];
        float rg = 1.f / (1.f + __expf(-rp));
        float zg = 1.f / (1.f + __expf(-zp));
        float np = (float)igv[4 + p] + rg * hv;
        np = fminf(fmaxf(np, -30.f), 30.f);
        float e2 = __expf(2.f * np);
        float ng = (e2 - 1.f) / (e2 + 1.f);
        float hn = ng + zg * (hreg[p][r] - ng);
        if (k < len[r]) out[(size_t)(sa[r] + k) * 256 + jrow0 + p * 16] = hn;
        hreg[p][r] = fnext[r] ? 0.f : hn;
      }
    }
    __syncthreads();   // h_s/ig_s[bc] reads done; staged buffer bc^1 complete
#pragma unroll
    for (int p = 0; p < 2; ++p)
#pragma unroll
      for (int r = 0; r < 4; ++r)
        h_s[q * 4 + r][jrow0 + p * 16] = (__bf16)hreg[p][r];
    __syncthreads();   // h_s visible for next step
  }
}

__global__ void fin_copy(float* __restrict__ out) {
  int i = threadIdx.x;
  out[(size_t)TT * 256 + i] = out[((size_t)TT - 1) * 256 + i];
}

extern "C" void kernel_launch(void* const* d_in, const int* in_sizes, int n_in,
                              void* d_out, int out_size, void* d_ws, size_t ws_size,
                              hipStream_t stream) {
  const float* x      = (const float*)d_in[0];
  const float* state  = (const float*)d_in[1];
  const int*   start  = (const int*)d_in[2];
  const float* wih    = (const float*)d_in[4];
  const float* whh    = (const float*)d_in[5];
  const float* bias   = (const float*)d_in[6];
  const float* bias_n = (const float*)d_in[7];
  float* out = (float*)d_out;

  prep_w<<<256, 256, 0, stream>>>(wih, whh);
  prep_x<<<8192, 256, 0, stream>>>(x);
  gemm_ig<<<3072, 256, 0, stream>>>(bias);
  gru_scan<<<NBLK, 512, 0, stream>>>(state, start, bias_n, out);
  fin_copy<<<1, 256, 0, stream>>>(out);
}

// Round 4
// 335.335 us; speedup vs baseline: 1.1653x; 1.1653x over previous
//
#include <hip/hip_runtime.h>
#include <hip/hip_bf16.h>
#include <stdint.h>

#define TT   65536
#define NCH  16
#define CNOM 16
#define NBLK 256
#define ROWB 1664            // bytes per packed igate row (6*256 used + 128 pad)
#define CHPR 104             // 16B chunks per row
#define CHTOT (16 * CHPR)    // 1664 chunks per staging buffer

typedef __bf16 bf16x8 __attribute__((ext_vector_type(8)));
typedef float  f32x4  __attribute__((ext_vector_type(4)));
typedef int    i32x4  __attribute__((ext_vector_type(4)));

__device__ __bf16 g_wih[768 * 256];
__device__ __bf16 g_whh[768 * 256];
__device__ __bf16 g_xbf[TT * 256];
__device__ __align__(64) unsigned char g_ig[(size_t)TT * ROWB];

__device__ __forceinline__ void gl_lds16(const void* g, void* l) {
  __builtin_amdgcn_global_load_lds(
      (const __attribute__((address_space(1))) void*)(unsigned long long)(uintptr_t)g,
      (__attribute__((address_space(3))) void*)(unsigned int)(uintptr_t)l,
      16, 0, 0);
}

__device__ __forceinline__ bf16x8 as_bf16x8(i32x4 v) {
  bf16x8 r; __builtin_memcpy(&r, &v, 16); return r;
}
__device__ __forceinline__ float bfbits(uint32_t u) {
  float f; __builtin_memcpy(&f, &u, 4); return f;
}

__global__ void prep_w(const float* __restrict__ wih, const float* __restrict__ whh) {
  const int n = 768 * 256;
  for (int i = blockIdx.x * blockDim.x + threadIdx.x; i < n; i += gridDim.x * blockDim.x) {
    g_wih[i] = (__bf16)wih[i];
    g_whh[i] = (__bf16)whh[i];
  }
}

__global__ void prep_x(const float* __restrict__ x) {
  int i = (blockIdx.x * 256 + threadIdx.x) * 8;
  float4 a0 = *(const float4*)(x + i);
  float4 a1 = *(const float4*)(x + i + 4);
  bf16x8 v;
  v[0] = (__bf16)a0.x; v[1] = (__bf16)a0.y; v[2] = (__bf16)a0.z; v[3] = (__bf16)a0.w;
  v[4] = (__bf16)a1.x; v[5] = (__bf16)a1.y; v[6] = (__bf16)a1.z; v[7] = (__bf16)a1.w;
  *(bf16x8*)(g_xbf + i) = v;
}

// phase 1: igates = x @ W_ih^T + bias -> packed rows, fully coalesced writes.
// col = c*256 + unit; segment = col>>7 (0..5, 256B each);
// within segment: dword (((unit>>5)&3)*16 + (unit&15)), halves = (unit>>4)&1.
__global__ __launch_bounds__(256) void gemm_ig(const float* __restrict__ bias) {
  __shared__ __align__(16) __bf16 a_s[128 * 64];
  __shared__ __align__(16) __bf16 b_s[128 * 64];
  const int tid = threadIdx.x;
  const int w = tid >> 6, lane = tid & 63, l15 = lane & 15, q = lane >> 4;
  const int mt = blockIdx.x / 6, ntb = blockIdx.x - mt * 6;
  const int m0 = mt * 128, n0 = ntb * 128;
  const int wm = w >> 1, wn = w & 1;

  f32x4 acc[4][4];
#pragma unroll
  for (int a = 0; a < 4; ++a)
#pragma unroll
    for (int b = 0; b < 4; ++b) acc[a][b] = (f32x4){0.f, 0.f, 0.f, 0.f};

  for (int kc = 0; kc < 4; ++kc) {
#pragma unroll
    for (int i = 0; i < 4; ++i) {
      int pslot = i * 256 + tid;
      int row = pslot >> 3, cb = (pslot & 7) ^ (row & 7);
      gl_lds16((const char*)g_xbf + ((size_t)(m0 + row) * 256 + kc * 64) * 2 + cb * 16,
               (char*)a_s + (i * 256 + (tid & ~63)) * 16);
      gl_lds16((const char*)g_wih + ((size_t)(n0 + row) * 256 + kc * 64) * 2 + cb * 16,
               (char*)b_s + (i * 256 + (tid & ~63)) * 16);
    }
    __syncthreads();
#pragma unroll
    for (int ks = 0; ks < 2; ++ks) {
      bf16x8 af[4], bfr[4];
#pragma unroll
      for (int tm = 0; tm < 4; ++tm) {
        int row = wm * 64 + tm * 16 + l15;
        int cb = (ks * 4 + q) ^ (row & 7);
        af[tm] = *(const bf16x8*)((const char*)a_s + row * 128 + cb * 16);
      }
#pragma unroll
      for (int tn = 0; tn < 4; ++tn) {
        int row = wn * 64 + tn * 16 + l15;
        int cb = (ks * 4 + q) ^ (row & 7);
        bfr[tn] = *(const bf16x8*)((const char*)b_s + row * 128 + cb * 16);
      }
#pragma unroll
      for (int tm = 0; tm < 4; ++tm)
#pragma unroll
        for (int tn = 0; tn < 4; ++tn)
          acc[tm][tn] = __builtin_amdgcn_mfma_f32_16x16x32_bf16(af[tm], bfr[tn], acc[tm][tn], 0, 0, 0);
    }
    __syncthreads();
  }
  float bv[4];
#pragma unroll
  for (int tn = 0; tn < 4; ++tn) bv[tn] = bias[n0 + wn * 64 + tn * 16 + l15];
#pragma unroll
  for (int tm = 0; tm < 4; ++tm) {
#pragma unroll
    for (int tp = 0; tp < 2; ++tp) {
#pragma unroll
      for (int r = 0; r < 4; ++r) {
        int t = m0 + wm * 64 + tm * 16 + q * 4 + r;
        __bf16 lo = (__bf16)(acc[tm][tp * 2][r] + bv[tp * 2]);
        __bf16 hi = (__bf16)(acc[tm][tp * 2 + 1][r] + bv[tp * 2 + 1]);
        unsigned short ulo, uhi;
        __builtin_memcpy(&ulo, &lo, 2); __builtin_memcpy(&uhi, &hi, 2);
        uint32_t u = (uint32_t)ulo | ((uint32_t)uhi << 16);
        *(uint32_t*)(g_ig + (size_t)t * ROWB + ntb * 256 + (wn * 2 + tp) * 64 + l15 * 4) = u;
      }
    }
  }
}

// phase 2: the scan. W_hh pinned (256-VGPR budget forced); packed igates staged async.
__global__ __launch_bounds__(512)
__attribute__((amdgpu_waves_per_eu(2, 2)))
void gru_scan(const float* __restrict__ state, const int* __restrict__ start,
              const float* __restrict__ bias_n, float* __restrict__ out) {
  __shared__ __align__(16) __bf16 h_s[16][264];
  __shared__ __align__(16) unsigned char ig_s[2][16 * ROWB];
  __shared__ int flg_s[16 * 132];
  __shared__ int s_arr[17];

  const int tid = threadIdx.x;
  const int w = tid >> 6, lane = tid & 63, l15 = lane & 15, q = lane >> 4;
  const int jrow0 = w * 32 + l15;

  if (tid < 17) {
    int t = (blockIdx.x * NCH + tid) * CNOM;
    if (t > 0) { while (t < TT && start[t] == 0) t++; }
    s_arr[tid] = t;
  }
  for (int i = tid; i < 16 * 264; i += 512) (&h_s[0][0])[i] = (__bf16)0.f;
  __syncthreads();

  int sa[4], len[4];
#pragma unroll
  for (int r = 0; r < 4; ++r) {
    sa[r] = s_arr[q * 4 + r];
    len[r] = s_arr[q * 4 + r + 1] - sa[r];
  }
  int ML = 0;
  for (int m = 0; m < 16; ++m) { int L = s_arr[m + 1] - s_arr[m]; ML = L > ML ? L : ML; }

  // start-flag table: flg_s[m][kk] = start[s_arr[m]+kk] for kk<128
  for (int idx = tid; idx < 2048; idx += 512) {
    int m = idx >> 7, kk = idx & 127;
    int t = s_arr[m] + kk;
    flg_s[m * 132 + kk] = (t < TT) ? start[t] : 0;
  }

  // staging geometry: chunk c = it*512+tid -> (row, 16B offset)
  int srow[4], goff[4];
#pragma unroll
  for (int it = 0; it < 4; ++it) {
    int c = it * 512 + tid;
    int cc = c < CHTOT ? c : 0;
    int row = cc / CHPR;
    srow[it] = s_arr[row];
    goff[it] = (cc - row * CHPR) * 16;
  }

  const int start0 = start[0];
  if (blockIdx.x == 0 && tid < 256) h_s[0][tid] = start0 ? (__bf16)0.f : (__bf16)state[tid];

  // stage igates for k=0 into buf 0
#pragma unroll
  for (int it = 0; it < 4; ++it) {
    if (it < 3 || tid < CHTOT - 1536) {
      int t = srow[it]; t = t > TT - 1 ? TT - 1 : t;
      gl_lds16(g_ig + (size_t)t * ROWB + goff[it],
               (char*)&ig_s[0][0] + (it * 512 + (tid & ~63)) * 16);
    }
  }

  // W_hh fragments, pinned in VGPRs
  i32x4 whh_i[2][3][8];
#pragma unroll
  for (int p = 0; p < 2; ++p)
#pragma unroll
    for (int c = 0; c < 3; ++c) {
      const __bf16* rp = &g_whh[(c * 256 + w * 32 + p * 16 + l15) * 256 + q * 8];
#pragma unroll
      for (int ks = 0; ks < 8; ++ks) whh_i[p][c][ks] = *(const i32x4*)(rp + ks * 32);
    }
#pragma unroll
  for (int p = 0; p < 2; ++p)
#pragma unroll
    for (int c = 0; c < 3; ++c)
#pragma unroll
      for (int ks = 0; ks < 8; ++ks) asm volatile("" : "+v"(whh_i[p][c][ks]));

  const float bn2[2] = { bias_n[jrow0], bias_n[jrow0 + 16] };

  float hreg[2][4];
#pragma unroll
  for (int p = 0; p < 2; ++p)
#pragma unroll
    for (int r = 0; r < 4; ++r) hreg[p][r] = 0.f;
  if (blockIdx.x == 0 && q == 0 && !start0) {
    hreg[0][0] = state[jrow0];
    hreg[1][0] = state[jrow0 + 16];
  }
  const int cw = (w >> 2) * 256 + ((w & 3) * 16 + l15) * 4;  // lane const: seg sub-offset
  __syncthreads();

  for (int k = 0; k < ML; ++k) {
    const int bc = k & 1;
    // async prefetch igates(k+1) into the other buffer
#pragma unroll
    for (int it = 0; it < 4; ++it) {
      if (it < 3 || tid < CHTOT - 1536) {
        int t = srow[it] + k + 1; t = t > TT - 1 ? TT - 1 : t;
        gl_lds16(g_ig + (size_t)t * ROWB + goff[it],
                 (char*)&ig_s[bc ^ 1][0] + (it * 512 + (tid & ~63)) * 16);
      }
    }
    int fnext[4];
    if (k + 1 < 128) {
#pragma unroll
      for (int r = 0; r < 4; ++r) fnext[r] = flg_s[(q * 4 + r) * 132 + k + 1];
    } else {
#pragma unroll
      for (int r = 0; r < 4; ++r) {
        int t = sa[r] + k + 1; t = t > TT - 1 ? TT - 1 : t;
        fnext[r] = start[t];
      }
    }

    f32x4 acc[2][3];
#pragma unroll
    for (int p = 0; p < 2; ++p)
#pragma unroll
      for (int c = 0; c < 3; ++c) acc[p][c] = (f32x4){0.f, 0.f, 0.f, 0.f};
#pragma unroll
    for (int ks = 0; ks < 8; ++ks) {
      bf16x8 hf = *(const bf16x8*)&h_s[l15][ks * 32 + q * 8];
#pragma unroll
      for (int p = 0; p < 2; ++p)
#pragma unroll
        for (int c = 0; c < 3; ++c)
          acc[p][c] = __builtin_amdgcn_mfma_f32_16x16x32_bf16(
              hf, as_bf16x8(whh_i[p][c][ks]), acc[p][c], 0, 0, 0);
    }

    const unsigned char* igB = &ig_s[bc][0];
#pragma unroll
    for (int r = 0; r < 4; ++r) {
      int m = q * 4 + r;
      const unsigned char* bp = igB + m * ROWB + cw;
      uint32_t vr = *(const uint32_t*)(bp);
      uint32_t vz = *(const uint32_t*)(bp + 512);
      uint32_t vn = *(const uint32_t*)(bp + 1024);
#pragma unroll
      for (int p = 0; p < 2; ++p) {
        float igr = bfbits(p ? (vr & 0xffff0000u) : (vr << 16));
        float igz = bfbits(p ? (vz & 0xffff0000u) : (vz << 16));
        float ign = bfbits(p ? (vn & 0xffff0000u) : (vn << 16));
        float rp = acc[p][0][r] + igr;
        float zp = acc[p][1][r] + igz;
        float hv = acc[p][2][r] + bn2[p];
        float rg = 1.f / (1.f + __expf(-rp));
        float zg = 1.f / (1.f + __expf(-zp));
        float np = ign + rg * hv;
        np = fminf(fmaxf(np, -30.f), 30.f);
        float e2 = __expf(2.f * np);
        float ng = (e2 - 1.f) / (e2 + 1.f);
        float hn = ng + zg * (hreg[p][r] - ng);
        if (k < len[r]) out[(size_t)(sa[r] + k) * 256 + jrow0 + p * 16] = hn;
        hreg[p][r] = fnext[r] ? 0.f : hn;
      }
    }
    __syncthreads();   // h_s/ig_s[bc] reads done; prefetched buffer complete
#pragma unroll
    for (int p = 0; p < 2; ++p)
#pragma unroll
      for (int r = 0; r < 4; ++r)
        h_s[q * 4 + r][jrow0 + p * 16] = (__bf16)hreg[p][r];
    __syncthreads();   // h_s visible for next step
  }
}

__global__ void fin_copy(float* __restrict__ out) {
  int i = threadIdx.x;
  out[(size_t)TT * 256 + i] = out[((size_t)TT - 1) * 256 + i];
}

extern "C" void kernel_launch(void* const* d_in, const int* in_sizes, int n_in,
                              void* d_out, int out_size, void* d_ws, size_t ws_size,
                              hipStream_t stream) {
  const float* x      = (const float*)d_in[0];
  const float* state  = (const float*)d_in[1];
  const int*   start  = (const int*)d_in[2];
  const float* wih    = (const float*)d_in[4];
  const float* whh    = (const float*)d_in[5];
  const float* bias   = (const float*)d_in[6];
  const float* bias_n = (const float*)d_in[7];
  float* out = (float*)d_out;

  prep_w<<<256, 256, 0, stream>>>(wih, whh);
  prep_x<<<8192, 256, 0, stream>>>(x);
  gemm_ig<<<3072, 256, 0, stream>>>(bias);
  gru_scan<<<NBLK, 512, 0, stream>>>(state, start, bias_n, out);
  fin_copy<<<1, 256, 0, stream>>>(out);
}